// Round 6
// baseline (198.312 us; speedup 1.0000x reference)
//
#include <hip/hip_runtime.h>

// ---------------- constants for this problem ----------------
// N_NODES=100000, N_EDGES=1600000, IN_FEATS=128, H=4, D=32, HD=128, NUM_ETYPES=8, DROP_BLOCKS=4
// Bucket = 512 consecutive dst nodes (nbuk = ceil(N/512) = 196).
// csr2 entry: src[0:17) | etype[17:20) | (dst&511)[20:29)
// csr  entry: src[0:20) | etype[20:23)

typedef short short8 __attribute__((ext_vector_type(8)));
typedef float f32x4 __attribute__((ext_vector_type(4)));

__device__ inline unsigned short f2bf(float x) {
    unsigned u = __builtin_bit_cast(unsigned, x);
    u += 0x7FFFu + ((u >> 16) & 1u);   // RNE
    return (unsigned short)(u >> 16);
}

// K1: coarse bucket histogram (196 buckets of 512 nodes)
__global__ __launch_bounds__(256) void k_bcnt(const int* __restrict__ dst,
                                              unsigned* __restrict__ gcnt, int E) {
    __shared__ unsigned l[256];
    int tid = threadIdx.x;
    l[tid] = 0;
    __syncthreads();
    int base = blockIdx.x * 2048;
#pragma unroll
    for (int j = 0; j < 8; ++j) {
        int e = base + j * 256 + tid;
        if (e < E) atomicAdd(&l[(unsigned)dst[e] >> 9], 1u);
    }
    __syncthreads();
    if (l[tid]) atomicAdd(&gcnt[tid], l[tid]);
}

// K2: exclusive scan of bucket counts (single block, 256 >= nbuk)
__global__ __launch_bounds__(256) void k_bscan(const unsigned* __restrict__ gcnt,
                                               unsigned* __restrict__ gbase,
                                               unsigned* __restrict__ gcur) {
    __shared__ unsigned s[256];
    int t = threadIdx.x;
    unsigned orig = gcnt[t];
    s[t] = orig;
    __syncthreads();
    for (int of = 1; of < 256; of <<= 1) {
        unsigned v = (t >= of) ? s[t - of] : 0u;
        __syncthreads();
        s[t] += v;
        __syncthreads();
    }
    unsigned eb = s[t] - orig;
    gbase[t] = eb;
    gcur[t] = eb;
}

// K3: LDS-staged partition: group 4096-edge chunks by bucket in LDS, reserve
// per-bucket global space (1 atomic per block-bucket), flush coalesced.
__global__ __launch_bounds__(256) void k_part(const int* __restrict__ src,
                                              const int* __restrict__ dst,
                                              const int* __restrict__ ef,
                                              unsigned* __restrict__ gcur,
                                              unsigned* __restrict__ csr2,
                                              int E, int nbuk) {
    __shared__ unsigned lcnt[256];
    __shared__ unsigned lbase[256];
    __shared__ unsigned lcur[256];
    __shared__ unsigned gw2[256];
    __shared__ unsigned stp[4096];
    __shared__ unsigned short stb[4096];
    int tid = threadIdx.x;
    lcnt[tid] = 0;
    __syncthreads();

    int cb = blockIdx.x * 4096;
    int cc = E - cb; if (cc > 4096) cc = 4096;

    unsigned pay[16];
    unsigned short bk[16];
#pragma unroll
    for (int j = 0; j < 16; ++j) {
        int idx = j * 256 + tid;
        if (idx < cc) {
            int e = cb + idx;
            unsigned d = (unsigned)dst[e];
            pay[j] = (unsigned)src[e] | ((unsigned)ef[e] << 17) | ((d & 511u) << 20);
            bk[j] = (unsigned short)(d >> 9);
            atomicAdd(&lcnt[bk[j]], 1u);
        }
    }
    __syncthreads();
    // scan lcnt -> exclusive lbase
    lbase[tid] = lcnt[tid];
    __syncthreads();
    for (int of = 1; of < 256; of <<= 1) {
        unsigned v = (tid >= of) ? lbase[tid - of] : 0u;
        __syncthreads();
        lbase[tid] += v;
        __syncthreads();
    }
    unsigned eb = lbase[tid] - lcnt[tid];
    __syncthreads();
    lbase[tid] = eb;
    lcur[tid] = eb;
    __syncthreads();
    // LDS scatter: group by bucket
#pragma unroll
    for (int j = 0; j < 16; ++j) {
        int idx = j * 256 + tid;
        if (idx < cc) {
            unsigned lpos = atomicAdd(&lcur[bk[j]], 1u);
            stp[lpos] = pay[j];
            stb[lpos] = bk[j];
        }
    }
    // reserve global space
    if (tid < nbuk && lcnt[tid]) gw2[tid] = atomicAdd(&gcur[tid], lcnt[tid]);
    __syncthreads();
    // coalesced flush
#pragma unroll
    for (int j = 0; j < 16; ++j) {
        int i = j * 256 + tid;
        if (i < cc) {
            unsigned b = stb[i];
            csr2[gw2[b] + (i - lbase[b])] = stp[i];
        }
    }
}

// K4: per-bucket: count (node,etype), scan node degrees -> offs/deg/stats,
// then counting-sort into final node-grouped CSR (L2-hot region).
__global__ __launch_bounds__(256) void k_bsort2(const unsigned* __restrict__ csr2,
                                                const unsigned* __restrict__ gbase,
                                                const unsigned* __restrict__ gcnt,
                                                const float* __restrict__ emb,
                                                unsigned* __restrict__ csr,
                                                unsigned* __restrict__ offs,
                                                unsigned* __restrict__ deg,
                                                float* __restrict__ stats, int N) {
    __shared__ unsigned cnt8[512 * 8];   // 16 KB
    __shared__ unsigned degL[512];
    __shared__ unsigned offsL[512];
    __shared__ unsigned curL[512];
    __shared__ unsigned tmp[256];
    __shared__ float se[32];
    int b = blockIdx.x, tid = threadIdx.x;
    if (tid < 32) se[tid] = emb[tid];
#pragma unroll
    for (int i = 0; i < 16; ++i) cnt8[i * 256 + tid] = 0u;
    __syncthreads();
    unsigned r0 = gbase[b], r1 = r0 + gcnt[b];
    for (unsigned i = r0 + tid; i < r1; i += 256) {
        unsigned en = csr2[i];
        atomicAdd(&cnt8[((en >> 20) & 511u) * 8u + ((en >> 17) & 7u)], 1u);
    }
    __syncthreads();
    int n0 = tid * 2, n1 = tid * 2 + 1;
    unsigned d0 = 0, d1 = 0;
#pragma unroll
    for (int k = 0; k < 8; ++k) { d0 += cnt8[n0 * 8 + k]; d1 += cnt8[n1 * 8 + k]; }
    degL[n0] = d0; degL[n1] = d1;
    tmp[tid] = d0 + d1;
    __syncthreads();
    for (int of = 1; of < 256; of <<= 1) {
        unsigned v = (tid >= of) ? tmp[tid - of] : 0u;
        __syncthreads();
        tmp[tid] += v;
        __syncthreads();
    }
    unsigned eb = tmp[tid] - (d0 + d1);
    offsL[n0] = eb;        curL[n0] = eb;
    offsL[n1] = eb + d0;   curL[n1] = eb + d0;
    // per-node outputs + fused softmax stats
#pragma unroll
    for (int q = 0; q < 2; ++q) {
        int nl = tid * 2 + q;
        int gn = b * 512 + nl;
        if (gn < N) {
            offs[gn] = r0 + offsL[nl];
            unsigned dg = degL[nl];
            deg[gn] = dg;
            const unsigned* c = &cnt8[nl * 8];
#pragma unroll
            for (int h = 0; h < 4; ++h) {
                float m = -3.4e38f;
#pragma unroll
                for (int tt = 0; tt < 8; ++tt)
                    if (c[tt]) m = fmaxf(m, se[tt * 4 + h]);
                float s = 0.f;
#pragma unroll
                for (int tt = 0; tt < 8; ++tt)
                    if (c[tt]) s += (float)c[tt] * expf(se[tt * 4 + h] - m);
                stats[(size_t)gn * 8 + h] = m;
                stats[(size_t)gn * 8 + 4 + h] = dg ? (1.0f / s) : 0.0f;
            }
        }
    }
    __syncthreads();
    // counting-sort scatter within the (L2-hot) bucket region
    for (unsigned i = r0 + tid; i < r1; i += 256) {
        unsigned en = csr2[i];
        unsigned nlo = (en >> 20) & 511u;
        unsigned tt = (en >> 17) & 7u;
        unsigned pos = r0 + atomicAdd(&curL[nlo], 1u);
        csr[pos] = (en & 0x1FFFFu) | (tt << 20);
    }
}

// K5: attn_out (E, H, 4, 1) — thread per edge, 64 B contiguous store
__global__ __launch_bounds__(256) void k_attn_out(const int* __restrict__ e_feat,
                                                  const int* __restrict__ dst,
                                                  const float* __restrict__ emb,
                                                  const float* __restrict__ stats,
                                                  float4* __restrict__ ao, int E) {
    int e = blockIdx.x * 256 + threadIdx.x;
    if (e >= E) return;
    int tt = e_feat[e];
    int d = dst[e];
    const float4* st4 = (const float4*)(stats + (size_t)d * 8);
    float4 m4 = st4[0], i4 = st4[1];
    float4 ee = *(const float4*)(emb + tt * 4);
    float a0 = expf(ee.x - m4.x) * i4.x;
    float a1 = expf(ee.y - m4.y) * i4.y;
    float a2 = expf(ee.z - m4.z) * i4.z;
    float a3 = expf(ee.w - m4.w) * i4.w;
    float4* p = ao + (size_t)e * 4;
    p[0] = make_float4(a0, a0, a0, a0);
    p[1] = make_float4(a1, a1, a1, a1);
    p[2] = make_float4(a2, a2, a2, a2);
    p[3] = make_float4(a3, a3, a3, a3);
}

// K6: ft = feat @ W^T via bf16 MFMA; A-fragments loaded DIRECTLY from global
// (converted in-register), only W staged in LDS (bf16, swizzled). Output bf16.
__global__ __launch_bounds__(256) void k_gemm_mfma(const float* __restrict__ feat,
                                                   const float* __restrict__ W,
                                                   unsigned short* __restrict__ ftb, int N) {
    __shared__ unsigned short Bs[128 * 128];  // 32 KB
    int tid = threadIdx.x;
    int row0 = blockIdx.x * 128;

    // ---- stage W: fp32 -> bf16, swizzled (byte ^= (row&7)<<4) ----
#pragma unroll
    for (int it = 0; it < 16; ++it) {
        int i = it * 1024 + tid * 4;
        int r = i >> 7, c = i & 127;
        unsigned swz = (unsigned)((r & 7) << 4);
        float4 w4 = *(const float4*)(W + i);
        ushort4 wb;
        wb.x = f2bf(w4.x); wb.y = f2bf(w4.y); wb.z = f2bf(w4.z); wb.w = f2bf(w4.w);
        *(ushort4*)((char*)Bs + (((unsigned)(r * 256 + c * 2)) ^ swz)) = wb;
    }
    __syncthreads();

    int wv = tid >> 6, lane = tid & 63;
    int rl = lane & 15;
    unsigned swz = (unsigned)((lane & 7) << 4);
    int kq = (lane >> 4) * 16;          // LDS byte offset of this lane's k-octet
    int ko = (lane >> 4) * 8;           // element offset of k-octet

    int ra0 = row0 + wv * 32 + rl;
    int ra1 = ra0 + 16;
    bool v0 = ra0 < N, v1 = ra1 < N;
    const float* ap0 = feat + (size_t)ra0 * 128 + ko;
    const float* ap1 = feat + (size_t)ra1 * 128 + ko;

    f32x4 acc[2][8];
#pragma unroll
    for (int rt = 0; rt < 2; ++rt)
#pragma unroll
        for (int jt = 0; jt < 8; ++jt)
            acc[rt][jt] = (f32x4){0.f, 0.f, 0.f, 0.f};

    const char* Bb = (const char*)Bs;
#pragma unroll
    for (int kk = 0; kk < 4; ++kk) {
        int kb = kk * 64 + kq;
        short8 a[2], bfr[8];
        // A frags direct from global: 2x float4 fp32 -> 8 bf16
#pragma unroll
        for (int rt = 0; rt < 2; ++rt) {
            const float* ap = rt ? ap1 : ap0;
            bool v = rt ? v1 : v0;
            float4 lo = make_float4(0.f, 0.f, 0.f, 0.f), hi = lo;
            if (v) { lo = *(const float4*)(ap + kk * 32); hi = *(const float4*)(ap + kk * 32 + 4); }
            short8 t;
            t[0] = (short)f2bf(lo.x); t[1] = (short)f2bf(lo.y);
            t[2] = (short)f2bf(lo.z); t[3] = (short)f2bf(lo.w);
            t[4] = (short)f2bf(hi.x); t[5] = (short)f2bf(hi.y);
            t[6] = (short)f2bf(hi.z); t[7] = (short)f2bf(hi.w);
            a[rt] = t;
        }
#pragma unroll
        for (int jt = 0; jt < 8; ++jt)
            bfr[jt] = *(const short8*)(Bb + (((unsigned)((jt * 16 + rl) * 256 + kb)) ^ swz));
#pragma unroll
        for (int rt = 0; rt < 2; ++rt)
#pragma unroll
            for (int jt = 0; jt < 8; ++jt)
                acc[rt][jt] = __builtin_amdgcn_mfma_f32_16x16x32_bf16(a[rt], bfr[jt], acc[rt][jt], 0, 0, 0);
    }

    // ---- epilogue: D row=(lane>>4)*4+reg, col=lane&15; write bf16 ----
#pragma unroll
    for (int rt = 0; rt < 2; ++rt) {
        int gr0 = row0 + wv * 32 + rt * 16 + ((lane >> 4) << 2);
#pragma unroll
        for (int jt = 0; jt < 8; ++jt) {
            int col = jt * 16 + rl;
#pragma unroll
            for (int rg = 0; rg < 4; ++rg) {
                int gr = gr0 + rg;
                if (gr < N) ftb[(size_t)gr * 128 + col] = f2bf(acc[rt][jt][rg]);
            }
        }
    }
}

// K7: aggregate: wave per node, bf16 ft rows (256 B), CSR walk unrolled x8
__global__ __launch_bounds__(256) void k_agg(const unsigned* __restrict__ csr,
                                             const unsigned* __restrict__ offs,
                                             const unsigned* __restrict__ deg,
                                             const float* __restrict__ stats,
                                             const float* __restrict__ emb,
                                             const unsigned* __restrict__ ftu,  // bf16 pairs
                                             float* __restrict__ rst, int N) {
    __shared__ float wl[4 * 32];
    int tid = threadIdx.x;
    int wv = tid >> 6, lane = tid & 63;
    int n = blockIdx.x * 4 + wv;
    n = __builtin_amdgcn_readfirstlane(n);
    if (n < N && lane < 32) {
        int tt = lane >> 2, hh = lane & 3;
        float m = stats[(size_t)n * 8 + hh];
        float is = stats[(size_t)n * 8 + 4 + hh];
        wl[wv * 32 + lane] = expf(emb[tt * 4 + hh] - m) * is;
    }
    __syncthreads();
    if (n >= N) return;
    unsigned o = offs[n], dg = deg[n];
    int h = lane >> 4;
    const float* wlh = wl + wv * 32 + h;
    float accx = 0.f, accy = 0.f;
    unsigned k = o, end = o + dg;
    for (; k + 8 <= end; k += 8) {
        unsigned c[8], f[8];
#pragma unroll
        for (int j = 0; j < 8; ++j) c[j] = csr[k + j];
#pragma unroll
        for (int j = 0; j < 8; ++j) f[j] = ftu[(size_t)(c[j] & 0xFFFFFu) * 64 + lane];
#pragma unroll
        for (int j = 0; j < 8; ++j) {
            float a = wlh[(c[j] >> 20) * 4];
            accx = fmaf(a, __builtin_bit_cast(float, f[j] << 16), accx);
            accy = fmaf(a, __builtin_bit_cast(float, f[j] & 0xFFFF0000u), accy);
        }
    }
    for (; k < end; ++k) {
        unsigned c0 = csr[k];
        unsigned f0 = ftu[(size_t)(c0 & 0xFFFFFu) * 64 + lane];
        float a0 = wlh[(c0 >> 20) * 4];
        accx = fmaf(a0, __builtin_bit_cast(float, f0 << 16), accx);
        accy = fmaf(a0, __builtin_bit_cast(float, f0 & 0xFFFF0000u), accy);
    }
    ((float2*)rst)[(size_t)n * 64 + lane] = make_float2(accx, accy);
}

extern "C" void kernel_launch(void* const* d_in, const int* in_sizes, int n_in,
                              void* d_out, int out_size, void* d_ws, size_t ws_size,
                              hipStream_t stream) {
    const float* feat = (const float*)d_in[0];
    const float* W = (const float*)d_in[1];
    const float* emb = (const float*)d_in[2];
    const int* e_feat = (const int*)d_in[3];
    const int* src = (const int*)d_in[4];
    const int* dst = (const int*)d_in[5];
    int N = in_sizes[0] / 128;
    int E = in_sizes[3];
    int nbuk = (N + 511) >> 9;

    char* ws = (char*)d_ws;
    size_t off = 0;
    auto alloc = [&](size_t bytes) {
        void* p = ws + off;
        off = (off + bytes + 255) & ~(size_t)255;
        return p;
    };
    unsigned short* ftb = (unsigned short*)alloc((size_t)N * 128 * 2);
    float* stats = (float*)alloc((size_t)N * 8 * 4);
    unsigned* deg = (unsigned*)alloc((size_t)N * 4);
    unsigned* offs = (unsigned*)alloc((size_t)N * 4);
    unsigned* csr = (unsigned*)alloc((size_t)E * 4);
    unsigned* csr2 = (unsigned*)alloc((size_t)E * 4);
    unsigned* gcnt = (unsigned*)alloc(256 * 4);
    unsigned* gbase = (unsigned*)alloc(256 * 4);
    unsigned* gcur = (unsigned*)alloc(256 * 4);

    float* rst = (float*)d_out;
    float4* ao = (float4*)((float*)d_out + (size_t)N * 128);

    hipMemsetAsync(gcnt, 0, 256 * 4, stream);

    k_bcnt<<<(E + 2047) / 2048, 256, 0, stream>>>(dst, gcnt, E);
    k_bscan<<<1, 256, 0, stream>>>(gcnt, gbase, gcur);
    k_part<<<(E + 4095) / 4096, 256, 0, stream>>>(src, dst, e_feat, gcur, csr2, E, nbuk);
    k_bsort2<<<nbuk, 256, 0, stream>>>(csr2, gbase, gcnt, emb, csr, offs, deg, stats, N);
    k_gemm_mfma<<<(N + 127) / 128, 256, 0, stream>>>(feat, W, ftb, N);
    k_attn_out<<<(E + 255) / 256, 256, 0, stream>>>(e_feat, dst, emb, stats, ao, E);
    k_agg<<<(N + 3) / 4, 256, 0, stream>>>(csr, offs, deg, stats, emb, (const unsigned*)ftb, rst, N);
}